// Round 5
// baseline (109.373 us; speedup 1.0000x reference)
//
#include <hip/hip_runtime.h>
#include <stdint.h>

#define BATCH 16
#define NPROP 16384
#define NGT   128
#define NSAMP 256
#define NFG   64
#define GCAP  512
#define PCAP  8192   // dense pos LDS cap (64 KB)
#define NCAP  4096   // dense neg LDS cap (32 KB)
#define NBLK  128    // k_compute blocks per batch
#define BPB   128    // proposals per block

typedef unsigned long long ull;

// ---------- threefry2x32 block (key 0,1) ----------
__device__ __forceinline__ void thr_block(uint32_t c0, uint32_t c1,
                                          uint32_t* o0, uint32_t* o1) {
    const uint32_t k0 = 0u, k1 = 1u, ks2 = 0x1BD11BDBu; // 0^1^0x1BD11BDA
    uint32_t x0 = c0 + k0, x1 = c1 + k1;
#define RND(d) { x0 += x1; x1 = (x1 << d) | (x1 >> (32 - d)); x1 ^= x0; }
    RND(13) RND(15) RND(26) RND(6)   x0 += k1;  x1 += ks2 + 1u;
    RND(17) RND(29) RND(16) RND(24)  x0 += ks2; x1 += k0 + 2u;
    RND(13) RND(15) RND(26) RND(6)   x0 += k0;  x1 += k1 + 3u;
    RND(17) RND(29) RND(16) RND(24)  x0 += k1;  x1 += ks2 + 4u;
    RND(13) RND(15) RND(26) RND(6)   x0 += ks2; x1 += k0 + 5u;
#undef RND
    *o0 = x0; *o1 = x1;
}

__device__ __forceinline__ uint32_t thr_part_xor(uint32_t f) {
    uint32_t a, b; thr_block(0u, f, &a, &b);
    return a ^ b;
}

// list entry (u64): [44]=isPos, [43:21]=r mantissa (bits>>9), [20:7]=16383-n, [6:0]=argmax gt
// slabs per batch: 0=pos, 1=neg, 2=ignore; entries segmented per block: [blk*BPB + i]
__global__ void __launch_bounds__(256) k_compute(
    const float* __restrict__ props, const float* __restrict__ gts,
    ull* __restrict__ lists, uint32_t* __restrict__ cntblk)
{
#pragma clang fp contract(off)
    const int b = blockIdx.y;
    const int blk = blockIdx.x;
    const int tid = threadIdx.x;
    const int half = tid & 1;                 // 2 lanes per proposal: GTs 0-63 / 64-127
    const int n = blk * BPB + (tid >> 1);
    // SoA GT tile, odd half at +65 so even/odd lanes hit disjoint banks (no conflicts)
    __shared__ float2 sA[130];   // (x1,y1)
    __shared__ float2 sB[130];   // (x2,y2)
    __shared__ float  sag[130];
    __shared__ uint32_t wc[3][4], we_s[3][4];
    if (tid < NGT) {
        float4 g = ((const float4*)gts)[(size_t)b * NGT + tid];
        int idx = (tid < 64) ? tid : tid + 1;
        sA[idx] = make_float2(g.x, g.y);
        sB[idx] = make_float2(g.z, g.w);
        sag[idx] = (g.z - g.x) * (g.w - g.y);
    }
    __syncthreads();
    const float4 pb = ((const float4*)props)[(size_t)b * NPROP + n];
    const float ap = (pb.z - pb.x) * (pb.w - pb.y);
    const int base  = half ? 65 : 0;
    const int gbias = half ? 64 : 0;

    // pass 1: overlap masks. hit <=> w>0 && h>0 (sign tests are rounding-exact)
    uint32_t m0 = 0, m1 = 0;
    #pragma unroll 4
    for (int i = 0; i < 32; ++i) {
        const float2 a = sA[base + i];
        const float2 c = sB[base + i];
        uint32_t hit = (fminf(pb.z, c.x) > fmaxf(pb.x, a.x)) &
                       (fminf(pb.w, c.y) > fmaxf(pb.y, a.y));
        m0 |= hit << i;
    }
    #pragma unroll 4
    for (int i = 0; i < 32; ++i) {
        const float2 a = sA[base + 32 + i];
        const float2 c = sB[base + 32 + i];
        uint32_t hit = (fminf(pb.z, c.x) > fmaxf(pb.x, a.x)) &
                       (fminf(pb.w, c.y) > fmaxf(pb.y, a.y));
        m1 |= hit << i;
    }

    // pass 2: exact IEEE IoU only for hits. Non-hits have iou == +0, which never
    // beats best (init 0, bg = first index) under the original strict-> first-max.
    float best = 0.0f; int bg = gbias;
    while (m0) {
        int i = __builtin_ctz(m0); m0 &= m0 - 1;
        const float2 a = sA[base + i];
        const float2 c = sB[base + i];
        float w  = fmaxf(fminf(pb.z, c.x) - fmaxf(pb.x, a.x), 0.0f);
        float hh = fmaxf(fminf(pb.w, c.y) - fmaxf(pb.y, a.y), 0.0f);
        float inter = w * hh;
        float un = fmaxf(ap + sag[base + i] - inter, 1e-8f);
        float iou = inter / un;                   // IEEE f32 div = numpy bits
        if (iou > best) { best = iou; bg = gbias + i; }
    }
    while (m1) {
        int i = 32 + __builtin_ctz(m1); m1 &= m1 - 1;
        const float2 a = sA[base + i];
        const float2 c = sB[base + i];
        float w  = fmaxf(fminf(pb.z, c.x) - fmaxf(pb.x, a.x), 0.0f);
        float hh = fmaxf(fminf(pb.w, c.y) - fmaxf(pb.y, a.y), 0.0f);
        float inter = w * hh;
        float un = fmaxf(ap + sag[base + i] - inter, 1e-8f);
        float iou = inter / un;
        if (iou > best) { best = iou; bg = gbias + i; }
    }

    // merge halves: even lane owns result; strict > keeps half0 on float-ties (lower gt idx)
    float ob = __shfl_xor(best, 1);
    int  obg = __shfl_xor(bg, 1);
    if (half == 0 && ob > best) { best = ob; bg = obg; }

    uint32_t lab = (best >= 0.5f) ? 2u : ((best < 0.1f) ? 1u : 0u);
    const uint32_t f = (uint32_t)b * NPROP + (uint32_t)n;
    uint32_t mant = thr_part_xor(f) >> 9;
    ull entry = ((ull)(lab == 2u) << 44) | ((ull)mant << 21)
              | ((ull)(16383u - (uint32_t)n) << 7) | (ull)(uint32_t)bg;

    const bool isEven = (half == 0);
    bool cP = isEven && (lab == 2u);
    bool cN = isEven && (lab == 1u);
    bool cI = isEven && (lab == 0u);
    ull mP = __ballot(cP), mN = __ballot(cN), mI = __ballot(cI);
    const int w = tid >> 6;
    const uint32_t lane = (uint32_t)tid & 63u;
    if (lane == 0) {
        wc[0][w] = (uint32_t)__popcll(mP);
        wc[1][w] = (uint32_t)__popcll(mN);
        wc[2][w] = (uint32_t)__popcll(mI);
    }
    __syncthreads();
    if (tid < 3) {      // per-block NON-atomic counts: every slot written -> no k_zero
        uint32_t e = 0;
        #pragma unroll
        for (int i = 0; i < 4; i++) { we_s[tid][i] = e; e += wc[tid][i]; }
        cntblk[((size_t)b * NBLK + blk) * 4 + tid] = e;
    }
    __syncthreads();
    ull lt = lane ? (~0ull >> (64u - lane)) : 0ull;
    ull* slab = lists + (size_t)b * 3 * NPROP;
    const uint32_t segB = (uint32_t)blk * BPB;
    if (cP) slab[0 * NPROP + segB + we_s[0][w] + (uint32_t)__popcll(mP & lt)] = entry;
    if (cN) slab[1 * NPROP + segB + we_s[1][w] + (uint32_t)__popcll(mN & lt)] = entry;
    if (cI) slab[2 * NPROP + segB + we_s[2][w] + (uint32_t)__popcll(mI & lt)] = entry;
}

__global__ void __launch_bounds__(1024) k_select(
    const float* __restrict__ props, const float* __restrict__ gts,
    const ull* __restrict__ lists, const uint32_t* __restrict__ cntblk,
    float* __restrict__ out)
{
#pragma clang fp contract(off)
    const int b = blockIdx.x;
    const int tid = threadIdx.x;
    __shared__ ull      dpos[PCAP];      // 64 KB dense pos
    __shared__ ull      dneg[NCAP];      // 32 KB dense neg
    __shared__ uint32_t hist[2048];      // 8 KB
    __shared__ ull      gat[GCAP];       // 4 KB
    __shared__ ull      selk[NSAMP];     // 2 KB
    __shared__ uint32_t sela[NSAMP];     // 1 KB
    __shared__ uint32_t bc[NBLK * 4];    // 2 KB per-block counts
    __shared__ uint32_t preP[NBLK], preN[NBLK];
    __shared__ uint32_t sh_dig, sh_k, sh_cnt_in, gcnt, selc;
    __shared__ uint32_t totP, totN, totI;
    __shared__ ull sh_thr;

    const ull* Spos = lists + (size_t)b * 3 * NPROP;
    const ull* Sneg = Spos + NPROP;
    const ull* Sign = Sneg + NPROP;
    if (tid < NBLK * 4) bc[tid] = cntblk[(size_t)b * NBLK * 4 + tid];
    if (tid == 0) selc = 0;
    __syncthreads();
    if (tid < 3) {       // serial per-class prefix over 128 blocks (trivial)
        uint32_t run = 0;
        for (int blk = 0; blk < NBLK; ++blk) {
            uint32_t v = bc[blk * 4 + tid];
            if (tid == 0) preP[blk] = run;
            else if (tid == 1) preN[blk] = run;
            run += v;
        }
        if (tid == 0) totP = run; else if (tid == 1) totN = run; else totI = run;
    }
    __syncthreads();
    const uint32_t npos = totP, nneg = totN, nig = totI;
    const bool posL = (npos <= PCAP), negL = (nneg <= NCAP);
    // densify pos/neg into LDS (segmented -> dense), one pass over 16K slots
    for (uint32_t s = tid; s < NPROP; s += 1024) {
        uint32_t blk = s >> 7, i = s & 127u;
        if (posL && i < bc[blk * 4 + 0]) dpos[preP[blk] + i] = Spos[s];
        if (negL && i < bc[blk * 4 + 1]) dneg[preN[blk] + i] = Sneg[s];
    }
    __syncthreads();

    const uint32_t mPos = posL ? npos : NPROP;
    const uint32_t mNeg = negL ? nneg : NPROP;
    auto posEnt = [&](uint32_t j, bool& e) -> ull {
        if (posL) { e = true; return dpos[j]; }
        e = (j & 127u) < bc[(j >> 7) * 4 + 0];
        return e ? Spos[j] : 0ull;
    };
    auto negEnt = [&](uint32_t j, bool& e) -> ull {
        if (negL) { e = true; return dneg[j]; }
        e = (j & 127u) < bc[(j >> 7) * 4 + 1];
        return e ? Sneg[j] : 0ull;
    };

    auto keyA_of = [](ull e) -> ull {    // raw (mant, invn): jnp stable argsort on r
        return (((e >> 21) & 0x7FFFFFull) << 14) | ((e >> 7) & 0x3FFFull);
    };

    auto locate = [&](uint32_t k) {      // boundary bin for k-th largest, wave 0
        if (tid < 64) {
            const uint32_t lane = (uint32_t)tid;
            uint32_t cs = 0;
            if (lane < 32) {
                const uint32_t base = lane * 64u;
                #pragma unroll 8
                for (uint32_t i = 0; i < 64; i++) cs += hist[base + i];
            }
            uint32_t s = cs;
            #pragma unroll
            for (int off = 1; off < 32; off <<= 1) {
                uint32_t t = __shfl_down(s, off);
                if (lane + off < 32) s += t;
            }
            uint32_t sExcl = s - cs;
            bool cond = (lane < 32) && (sExcl < k) && (k <= s);
            ull ball = __ballot(cond);
            uint32_t cstar = (uint32_t)(__ffsll((unsigned long long)ball) - 1);
            uint32_t kc = (uint32_t)__shfl((int)(k - sExcl), (int)cstar);
            uint32_t val = hist[cstar * 64u + lane];
            uint32_t fi = val;
            #pragma unroll
            for (int off = 1; off < 64; off <<= 1) {
                uint32_t t = __shfl_down(fi, off);
                if (lane + off < 64) fi += t;
            }
            uint32_t fExcl = fi - val;
            bool cond2 = (fExcl < kc) && (kc <= fi);
            ull ball2 = __ballot(cond2);
            uint32_t bstar = (uint32_t)(__ffsll((unsigned long long)ball2) - 1);
            if (lane == bstar) {
                sh_dig = cstar * 64u + lane;
                sh_k = kc - fExcl;
                sh_cnt_in = val;
            }
        }
    };

    // select k-th largest over m elements (key/elig via functor)
    auto radix = [&](auto&& kf, uint32_t m, uint32_t k, int shift) -> ull {
        if (m <= GCAP) {   // direct path: gather all eligible, rank-select
            if (tid == 0) gcnt = 0;
            __syncthreads();
            for (uint32_t j = tid; j < m; j += 1024) {
                bool e; ull key = kf(j, e);
                if (e) { uint32_t s = atomicAdd(&gcnt, 1u); gat[s] = key; }
            }
            __syncthreads();
            uint32_t gc = gcnt;
            if (tid < (int)gc) {
                ull x = gat[tid];
                uint32_t r = 0;
                for (uint32_t j = 0; j < gc; j++) r += (gat[j] > x);
                if (r == k - 1) sh_thr = x;
            }
            __syncthreads();
            return sh_thr;
        }
        ull prefix = 0, mask = 0;
        for (;;) {
            hist[tid] = 0; hist[tid + 1024] = 0;
            __syncthreads();
            for (uint32_t j = tid; j < m; j += 1024) {
                bool e; ull key = kf(j, e);
                if (e && ((key ^ prefix) & mask) == 0)
                    atomicAdd(&hist[(uint32_t)(key >> shift) & 2047u], 1u);
            }
            __syncthreads();
            locate(k);
            __syncthreads();
            uint32_t dig = sh_dig, kk = sh_k, cnt = sh_cnt_in;
            prefix |= ((ull)dig) << shift;
            mask   |= 2047ull << shift;
            if (cnt <= GCAP || shift == 0) {
                if (tid == 0) gcnt = 0;
                __syncthreads();
                for (uint32_t j = tid; j < m; j += 1024) {
                    bool e; ull key = kf(j, e);
                    if (e && ((key ^ prefix) & mask) == 0) {
                        uint32_t s = atomicAdd(&gcnt, 1u);
                        if (s < GCAP) gat[s] = key;
                    }
                }
                __syncthreads();
                uint32_t gc = (gcnt < GCAP) ? gcnt : GCAP;
                if (tid < (int)gc) {
                    ull x = gat[tid];
                    uint32_t r = 0;
                    for (uint32_t j = 0; j < gc; j++) r += (gat[j] > x);
                    if (r == kk - 1) sh_thr = x;
                }
                __syncthreads();
                return sh_thr;
            } else {
                k = kk;
                shift = (shift >= 11) ? shift - 11 : 0;
                __syncthreads();
            }
        }
    };

    // ---- phase 0: thrA = 64th-largest keyA among positives (only if npos > 64)
    ull thrA = 0;
    if (npos > NFG) {
        thrA = radix([&](uint32_t j, bool& e) -> ull {
            ull ent = posEnt(j, e); return keyA_of(ent); }, mPos, NFG, 26);
    }

    // exact jnp prio keys: f32 bits of (cls + r), rounding included
    auto keyB_pos = [&](ull ent) -> ull {
        uint32_t mant = (uint32_t)((ent >> 21) & 0x7FFFFFull);
        uint32_t invn = (uint32_t)((ent >> 7) & 0x3FFFull);
        float r = __uint_as_float(0x3F800000u | mant) - 1.0f;
        uint32_t cls = (keyA_of(ent) >= thrA) ? 3u : 1u;
        float prio = (float)cls + r;
        return (((ull)__float_as_uint(prio)) << 14) | (ull)invn;
    };
    auto keyB_neg = [](ull ent) -> ull {
        uint32_t mant = (uint32_t)((ent >> 21) & 0x7FFFFFull);
        uint32_t invn = (uint32_t)((ent >> 7) & 0x3FFFull);
        float r = __uint_as_float(0x3F800000u | mant) - 1.0f;
        float prio = 2.0f + r;
        return (((ull)__float_as_uint(prio)) << 14) | (ull)invn;
    };
    auto keyB_ign = [](ull ent) -> ull {
        uint32_t mant = (uint32_t)((ent >> 21) & 0x7FFFFFull);
        uint32_t invn = (uint32_t)((ent >> 7) & 0x3FFFull);
        float r = __uint_as_float(0x3F800000u | mant) - 1.0f;
        float prio = 0.0f + r;
        return (((ull)__float_as_uint(prio)) << 14) | (ull)invn;
    };

    // ---- phase 1: threshold for the 256-cut (boundary class analytic)
    const uint32_t c3 = (npos < NFG) ? npos : NFG;
    const uint32_t c2 = nneg;
    const uint32_t npn = npos + nneg;
    uint32_t clsStar = (npn >= NSAMP) ? ((NSAMP <= c3 + c2) ? 2u : 1u) : 0u;
    ull thrB = 0;
    if (clsStar == 2u) {
        // shift 26: bin = bits[22:12] + carry -> monotone 0..1024 (incl. 3.0 carry)
        thrB = radix([&](uint32_t j, bool& e) -> ull {
            ull ent = negEnt(j, e); return keyB_neg(ent); }, mNeg, NSAMP - c3, 26);
    } else if (clsStar == 1u) {
        thrB = radix([&](uint32_t j, bool& e) -> ull {
            ull ent = posEnt(j, e);
            ull kb = keyB_pos(ent);
            e = e && ((kb >> 14) < 0x40000000ull);   // cls1 only (prio < 2.0)
            return kb; }, mPos, NSAMP - c3 - c2, 26);
    } else {
        thrB = radix([&](uint32_t j, bool& e) -> ull {
            e = (j & 127u) < bc[(j >> 7) * 4 + 2];
            return e ? keyB_ign(Sign[j]) : 0ull; }, NPROP, NSAMP - npn, 34);
    }
    __syncthreads();

    // ---- compact: exactly NSAMP keys (keys unique)
    auto push = [&](ull key, ull ent, uint32_t fg) {
        uint32_t s = atomicAdd(&selc, 1u);
        if (s < NSAMP) { selk[s] = key; sela[s] = (fg << 7) | (uint32_t)(ent & 0x7Full); }
    };
    for (uint32_t j = tid; j < mPos; j += 1024) {
        bool e; ull ent = posEnt(j, e);
        if (!e) continue;
        ull key = keyB_pos(ent);
        if (clsStar == 0u || key >= thrB) push(key, ent, 1u);
    }
    for (uint32_t j = tid; j < mNeg; j += 1024) {
        bool e; ull ent = negEnt(j, e);
        if (!e) continue;
        ull key = keyB_neg(ent);
        if (clsStar == 0u || key >= thrB) push(key, ent, 0u);
    }
    if (clsStar == 0u) {
        for (uint32_t j = tid; j < NPROP; j += 1024) {
            if (((j & 127u) < bc[(j >> 7) * 4 + 2])) {
                ull ent = Sign[j];
                ull key = keyB_ign(ent);
                if (key >= thrB) push(key, ent, 0u);
            }
        }
    }
    __syncthreads();

    // ---- rank-scatter: output row = count of greater keys (desc sort position)
    if (tid < NSAMP) {
        ull x = selk[tid];
        uint32_t r = 0;
        for (int j = 0; j < NSAMP; j++) r += (selk[j] > x);
        uint32_t n = 16383u - (uint32_t)(x & 0x3FFFull);
        uint32_t aux = sela[tid];
        uint32_t bg = aux & 0x7Fu;
        const int isfg = (int)((aux >> 7) & 1u);
        const float4 pb = ((const float4*)props)[(size_t)b * NPROP + n];
        const float4 gb = ((const float4*)gts)[(size_t)b * NGT + bg];
        const size_t O_ROI = 0;
        const size_t O_LBL = (size_t)BATCH * NSAMP * 4;
        const size_t O_TGT = O_LBL + (size_t)BATCH * NSAMP;
        const size_t O_INW = O_TGT + (size_t)BATCH * NSAMP * 4;
        const size_t O_OUW = O_INW + (size_t)BATCH * NSAMP * 4;
        const size_t row = (size_t)b * NSAMP + r;
        out[O_ROI + row * 4 + 0] = pb.x;
        out[O_ROI + row * 4 + 1] = pb.y;
        out[O_ROI + row * 4 + 2] = pb.z;
        out[O_ROI + row * 4 + 3] = pb.w;
        out[O_LBL + row] = isfg ? 1.0f : 0.0f;
        float rw  = pb.z - pb.x, rh = pb.w - pb.y;
        float gw  = gb.z - gb.x, gh = gb.w - gb.y;
        out[O_TGT + row * 4 + 0] = ((gb.x + gb.z) * 0.5f - (pb.x + pb.z) * 0.5f) / rw;
        out[O_TGT + row * 4 + 1] = ((gb.y + gb.w) * 0.5f - (pb.y + pb.w) * 0.5f) / rh;
        out[O_TGT + row * 4 + 2] = logf(gw / rw);
        out[O_TGT + row * 4 + 3] = logf(gh / rh);
        float wv = isfg ? 1.0f : 0.0f;
        for (int c = 0; c < 4; c++) {
            out[O_INW + row * 4 + c] = wv;
            out[O_OUW + row * 4 + c] = wv;
        }
    }
}

extern "C" void kernel_launch(void* const* d_in, const int* in_sizes, int n_in,
                              void* d_out, int out_size, void* d_ws, size_t ws_size,
                              hipStream_t stream) {
    (void)in_sizes; (void)n_in; (void)out_size; (void)ws_size;
    const float* props = (const float*)d_in[0];
    const float* gts   = (const float*)d_in[1];
    ull* lists = (ull*)d_ws;                                         // 16*3*16384*8 = 6 MB
    uint32_t* cntblk = (uint32_t*)((char*)d_ws + (size_t)BATCH * 3 * NPROP * 8); // 32 KB
    float* out = (float*)d_out;

    dim3 gridA(NPROP / BPB, BATCH);   // (128, 16)
    k_compute<<<gridA, 256, 0, stream>>>(props, gts, lists, cntblk);
    k_select<<<BATCH, 1024, 0, stream>>>(props, gts, lists, cntblk, out);
}